// Round 17
// baseline (80.539 us; speedup 1.0000x reference)
//
#include <hip/hip_runtime.h>
#include <hip/hip_bf16.h>

// ILA layer (fp32 I/O): key = W@ft, query = W@fk (1x1 conv, shared W),
// sim[p,k] = <query[p], key[neighbor_k(p)]> over 9x9 window (zero-padded keys),
// weight = softmax_k(sim)  (OOB entries participate with sim=0),
// out[c,p] = sum_k weight[k] * ft[c, neighbor_k(p)]  (zero-padded ft).
// n=2, c=128, h=w=64, L=9 (81 neighbors).
// R17 = R14 structure - barrier B2c, with XOR-swizzled stride-128 ftl so that
// ftl [0,36864) is PROVABLY disjoint from simbF [36864,39456)  (R16's race fixed).

#define Hh 64
#define Ww 64
#define Cc 128
#define Nn 2
#define KK 81
#define HW (Hh * Ww)          // 4096
#define CHW (Cc * HW)         // 524288
#define P_TOT (Nn * HW)       // 8192

typedef _Float16 h8 __attribute__((ext_vector_type(8)));
typedef _Float16 h4 __attribute__((ext_vector_type(4)));
typedef float f4v __attribute__((ext_vector_type(4)));

// ---------------- Kernel A: projection via MFMA (R14-measured version, unchanged).
__global__ __launch_bounds__(256) void proj_kernel(const float* __restrict__ ft,
                                                   const float* __restrict__ fk,
                                                   const float* __restrict__ Wm,
                                                   _Float16* __restrict__ Qbuf,
                                                   _Float16* __restrict__ Kbuf,
                                                   _Float16* __restrict__ fth) {
    __shared__ __align__(16) _Float16 Wth[128 * 136];  // [o][i] fp16 (== B[k][n] view)
    __shared__ __align__(16) _Float16 xkh[32 * 136];   // [px][c] fp16
    __shared__ __align__(16) _Float16 xqh[32 * 136];
    const int t = threadIdx.x;
    const int p0 = blockIdx.x * 32;       // 4096 % 32 == 0: never crosses n
    const int nn = p0 >> 12;
    const int gbase = nn * CHW + (p0 & 4095);

#pragma unroll 4
    for (int e = t; e < 4096; e += 256) {             // stage W -> fp16
        const int n = e >> 5, ch = e & 31;
        const float4 v = *(const float4*)&Wm[n * 128 + (ch << 2)];
        h4 hv; hv[0] = (_Float16)v.x; hv[1] = (_Float16)v.y;
               hv[2] = (_Float16)v.z; hv[3] = (_Float16)v.w;
        *(h4*)&Wth[n * 136 + (ch << 2)] = hv;
    }
#pragma unroll 4
    for (int e = t; e < 1024; e += 256) {             // stage x -> fp16 px-major
        const int c = e >> 3, pc = e & 7;
        const float4 vk = *(const float4*)&ft[gbase + c * HW + (pc << 2)];
        const float4 vq = *(const float4*)&fk[gbase + c * HW + (pc << 2)];
        const int px = pc << 2;
        xkh[(px    ) * 136 + c] = (_Float16)vk.x;
        xkh[(px + 1) * 136 + c] = (_Float16)vk.y;
        xkh[(px + 2) * 136 + c] = (_Float16)vk.z;
        xkh[(px + 3) * 136 + c] = (_Float16)vk.w;
        xqh[(px    ) * 136 + c] = (_Float16)vq.x;
        xqh[(px + 1) * 136 + c] = (_Float16)vq.y;
        xqh[(px + 2) * 136 + c] = (_Float16)vq.z;
        xqh[(px + 3) * 136 + c] = (_Float16)vq.w;
    }
    __syncthreads();

#pragma unroll
    for (int e = t; e < 512; e += 256) {              // fth: coalesced h8 copies
        const int px = e >> 4, cq = e & 15;
        *(h8*)&fth[(size_t)(p0 + px) * 128 + (cq << 3)] =
            *(const h8*)&xkh[px * 136 + (cq << 3)];
    }

    const int lane = t & 63, wv = t >> 6;
    const int quad = lane >> 4, l15 = lane & 15;
    const _Float16* xs = (wv >> 1) ? xqh : xkh;
    _Float16* dst = (wv >> 1) ? Qbuf : Kbuf;
    const int mt = wv & 1;
    const int abase = (mt * 16 + l15) * 136 + (quad << 3);
    const h8 a0 = *(const h8*)&xs[abase];
    const h8 a1 = *(const h8*)&xs[abase + 32];
    const h8 a2 = *(const h8*)&xs[abase + 64];
    const h8 a3 = *(const h8*)&xs[abase + 96];
#pragma unroll
    for (int nt = 0; nt < 8; ++nt) {
        const int bbase = (nt * 16 + l15) * 136 + (quad << 3);
        const h8 b0 = *(const h8*)&Wth[bbase];
        const h8 b1 = *(const h8*)&Wth[bbase + 32];
        const h8 b2 = *(const h8*)&Wth[bbase + 64];
        const h8 b3 = *(const h8*)&Wth[bbase + 96];
        f4v acc = {0.f, 0.f, 0.f, 0.f};
        acc = __builtin_amdgcn_mfma_f32_16x16x32_f16(a0, b0, acc, 0, 0, 0);
        acc = __builtin_amdgcn_mfma_f32_16x16x32_f16(a1, b1, acc, 0, 0, 0);
        acc = __builtin_amdgcn_mfma_f32_16x16x32_f16(a2, b2, acc, 0, 0, 0);
        acc = __builtin_amdgcn_mfma_f32_16x16x32_f16(a3, b3, acc, 0, 0, 0);
        const int col = nt * 16 + l15;
        const size_t rb = (size_t)(p0 + mt * 16 + (quad << 2)) * 128 + col;
#pragma unroll
        for (int r = 0; r < 4; ++r)
            dst[rb + (size_t)r * 128] = (_Float16)acc[r];
    }
}

// ---------------- Kernel B (fused): MFMA dots + softmax + weighting. 8-px row strip.
// LDS map: Ksw/ftl [0,36864) | Qsw [36864,38912); simbF [36864,39456) after B2a;
// simb aliases simbF after B3 | redM [39456,39584) | redS [39584,39712).
// ftl is XOR-swizzled stride-128 => exactly 36864 B, disjoint from simbF.  5 barriers.
__global__ __launch_bounds__(256, 4) void sim_weight_kernel(const _Float16* __restrict__ Qbuf,
                                                            const _Float16* __restrict__ Kbuf,
                                                            const _Float16* __restrict__ fth,
                                                            float* __restrict__ out) {
    __shared__ __align__(16) unsigned char smem[39712];
    _Float16* Ksw  = (_Float16*)smem;             // 18432 halves [0, 36864)
    _Float16* Qsw  = (_Float16*)(smem + 36864);   // 1024 halves; dead after dots
    _Float16* ftl  = (_Float16*)smem;             // XOR-swizzled [v][128] -> [0,36864)
    float*    simbF= (float*)(smem + 36864);      // [k][8] fp32 2592 B — alive B2a..B3
    _Float16* simb = (_Float16*)(smem + 36864);   // 648 halves — aliases simbF after B3
    float*    redM = (float*)(smem + 39456);      // 32 floats
    float*    redS = (float*)(smem + 39584);      // 32 floats

    const int t  = threadIdx.x;
    const int b  = blockIdx.x;
    const int x0 = (b & 7) << 3;
    const int y  = (b >> 3) & 63;
    const int nn = b >> 9;
    const int pg0 = (nn << 12) + (y << 6) + x0;

    // ---- stage K: zero-padded 9x16 window, h8 copies, XOR-swizzled slots
#pragma unroll 3
    for (int e = t; e < 144 * 16; e += 256) {
        const int v = e >> 4, ci = e & 15;
        const int gx = x0 + (v & 15) - 4;
        const int gy = y + (v >> 4) - 4;
        h8 val = {0, 0, 0, 0, 0, 0, 0, 0};
        if ((unsigned)gx < 64u && (unsigned)gy < 64u)
            val = *(const h8*)&Kbuf[(size_t)((nn << 12) + (gy << 6) + gx) * 128 + (ci << 3)];
        *(h8*)&Ksw[(v << 7) + ((ci ^ (v & 15)) << 3)] = val;
    }
    if (t < 128) {   // stage Q: 8 vectors x 16 chunks
        const int v = t >> 4, ci = t & 15;
        *(h8*)&Qsw[(v << 7) + ((ci ^ v) << 3)] =
            *(const h8*)&Qbuf[(size_t)(pg0 + v) * 128 + (ci << 3)];
    }
    __syncthreads();   // B1

    // ---- dots via MFMA: per r, S_r[xx][p] = sum_c Ksw[r*16+xx][c] * Q[p][c]
    // D: row=xx=quad*4+reg, col=p=lane&15 [R13 HW-verified layout].
    const int lane = t & 63, wv = t >> 6;
    const int quad = lane >> 4, l15 = lane & 15;
    const int qrow = l15 & 7;                 // clamp: cols 8-15 duplicate, never extracted
    h8 qb[4];
#pragma unroll
    for (int kc = 0; kc < 4; ++kc) {
        const int ci = (kc << 2) + quad;
        qb[kc] = *(const h8*)&Qsw[(qrow << 7) + ((ci ^ qrow) << 3)];
    }
    const int r0 = wv, r1 = wv + 4;           // r2 = 8 computed by all, extracted by wave 0
    f4v acc0 = {0.f,0.f,0.f,0.f}, acc1 = acc0, acc2 = acc0;
#pragma unroll
    for (int kc = 0; kc < 4; ++kc) {
        const int ci = (kc << 2) + quad;
        const h8 kA = *(const h8*)&Ksw[(((r0 << 4) + l15) << 7) + ((ci ^ l15) << 3)];
        const h8 kB = *(const h8*)&Ksw[(((r1 << 4) + l15) << 7) + ((ci ^ l15) << 3)];
        const h8 kC = *(const h8*)&Ksw[(((8  << 4) + l15) << 7) + ((ci ^ l15) << 3)];
        acc0 = __builtin_amdgcn_mfma_f32_16x16x32_f16(kA, qb[kc], acc0, 0, 0, 0);
        acc1 = __builtin_amdgcn_mfma_f32_16x16x32_f16(kB, qb[kc], acc1, 0, 0, 0);
        acc2 = __builtin_amdgcn_mfma_f32_16x16x32_f16(kC, qb[kc], acc2, 0, 0, 0);
    }
    __syncthreads();   // B2a: MFMA operand reads (Ksw+Qsw) done -> simbF may be written

    // extraction: valid iff p=l15<8 and dx=xx-p in [0,9); k = r*9+dx
#pragma unroll
    for (int reg = 0; reg < 4; ++reg) {
        const int xx = (quad << 2) + reg;
        const int dx = xx - l15;
        const bool ok = (l15 < 8) && (dx >= 0) && (dx < 9);
        if (ok)            simbF[(r0 * 9 + dx) * 8 + l15] = acc0[reg];
        if (ok)            simbF[(r1 * 9 + dx) * 8 + l15] = acc1[reg];
        if (ok && wv == 0) simbF[(8  * 9 + dx) * 8 + l15] = acc2[reg];
    }
    __syncthreads();   // B2b: simbF complete

    const int p = t & 7, kb = t >> 3;
    const bool has2 = (kb + 64 < KK);
    const float s0 = simbF[kb * 8 + p];
    const float s1 = simbF[(kb + 32) * 8 + p];
    const float s2 = has2 ? simbF[(kb + 64) * 8 + p] : 0.f;
    // no barrier: ftl writes [0,36864) are disjoint from simbF [36864,39456)

    // ---- restage ft: h8 copies fth[pixel] -> ftl, XOR-swizzled (same form as Ksw)
#pragma unroll 3
    for (int e = t; e < 144 * 16; e += 256) {
        const int v = e >> 4, ci = e & 15;
        const int gx = x0 + (v & 15) - 4;
        const int gy = y + (v >> 4) - 4;
        h8 val = {0, 0, 0, 0, 0, 0, 0, 0};
        if ((unsigned)gx < 64u && (unsigned)gy < 64u)
            val = *(const h8*)&fth[(size_t)((nn << 12) + (gy << 6) + gx) * 128 + (ci << 3)];
        *(h8*)&ftl[(v << 7) + ((ci ^ (v & 15)) << 3)] = val;
    }

    // ---- softmax in registers: reduce over lanes sharing p (bits 3..5 of lane id)
    float m = fmaxf(s0, s1);
    if (has2) m = fmaxf(m, s2);
#pragma unroll
    for (int off = 8; off <= 32; off <<= 1) m = fmaxf(m, __shfl_xor(m, off));
    if ((t & 56) == 0) redM[((t >> 6) << 3) + p] = m;   // one lane per (wave, p)
    __syncthreads();   // B3: covers ftl writes, redM writes, AND all simbF reads
    float mm = fmaxf(fmaxf(redM[p], redM[8 + p]), fmaxf(redM[16 + p], redM[24 + p]));
    const float e0 = __expf(s0 - mm);
    const float e1 = __expf(s1 - mm);
    const float e2 = has2 ? __expf(s2 - mm) : 0.f;
    simb[kb * 8 + p] = (_Float16)e0;              // safe: all simbF reads pre-B3
    simb[(kb + 32) * 8 + p] = (_Float16)e1;
    if (has2) simb[(kb + 64) * 8 + p] = (_Float16)e2;
    float s = e0 + e1 + e2;
#pragma unroll
    for (int off = 8; off <= 32; off <<= 1) s += __shfl_xor(s, off);
    if ((t & 56) == 0) redS[((t >> 6) << 3) + p] = s;
    __syncthreads();   // B4
    const float inv = 1.f / (redS[p] + redS[8 + p] + redS[16 + p] + redS[24 + p]);

    // ---- weighting: thread = (p, cq); 4 ch/thread; f from swizzled ftl (R15-verified
    // address form: v&15 == p+dx since p<=7, dx<=8); w scalar reads (R14 style).
    const int cq = t >> 3;
    const int ci = cq >> 1, sub = (cq & 1) << 2;
    float4 acc = make_float4(0, 0, 0, 0);
    for (int r = 0; r < 9; ++r) {
        const int vb = (r << 4) + p;
        const int k9 = r * 9;
#pragma unroll
        for (int dx = 0; dx < 9; ++dx) {
            const float w = (float)simb[(k9 + dx) * 8 + p];  // 8-lane broadcast
            const int v = vb + dx;
            const h4 f = *(const h4*)&ftl[(v << 7) + ((ci ^ (p + dx)) << 3) + sub];
            acc.x += (float)f[0] * w;
            acc.y += (float)f[1] * w;
            acc.z += (float)f[2] * w;
            acc.w += (float)f[3] * w;
        }
    }
    const size_t ob = (size_t)((nn * Cc + (cq << 2)) << 12) + (y << 6) + x0 + p;
    out[ob]          = acc.x * inv;
    out[ob + HW]     = acc.y * inv;
    out[ob + 2*HW]   = acc.z * inv;
    out[ob + 3*HW]   = acc.w * inv;
}

extern "C" void kernel_launch(void* const* d_in, const int* in_sizes, int n_in,
                              void* d_out, int out_size, void* d_ws, size_t ws_size,
                              hipStream_t stream) {
    const float* ft = (const float*)d_in[0];
    const float* fk = (const float*)d_in[1];
    const float* Wm = (const float*)d_in[2];
    float* out = (float*)d_out;

    _Float16* wsh  = (_Float16*)d_ws;    // 6 MB: Qh(2MB) + Kh(2MB) + fth(2MB)
    _Float16* Qbuf = wsh;                // [p][c]  8192*128 halves
    _Float16* Kbuf = wsh + 1048576;      // [p][c]  8192*128 halves
    _Float16* fth  = wsh + 2097152;      // fp16 ft, PIXEL-MAJOR [p][c]

    proj_kernel<<<256, 256, 0, stream>>>(ft, fk, Wm, Qbuf, Kbuf, fth);
    sim_weight_kernel<<<1024, 256, 0, stream>>>(Qbuf, Kbuf, fth, out);
}

// Round 18
// 78.997 us; speedup vs baseline: 1.0195x; 1.0195x over previous
//
#include <hip/hip_runtime.h>
#include <hip/hip_bf16.h>

// ILA layer (fp32 I/O): key = W@ft, query = W@fk (1x1 conv, shared W),
// sim[p,k] = <query[p], key[neighbor_k(p)]> over 9x9 window (zero-padded keys),
// weight = softmax_k(sim)  (OOB entries participate with sim=0),
// out[c,p] = sum_k weight[k] * ft[c, neighbor_k(p)]  (zero-padded ft).
// n=2, c=128, h=w=64, L=9 (81 neighbors).
// R18 = measured-best (round-14 bench, 79.2 us) + ftl REGISTER PREFETCH:
// the 9 fth loads issue right after B1 and overlap the MFMA dot phase;
// the post-B2c restage is pure LDS writes (second global-latency chain hidden).

#define Hh 64
#define Ww 64
#define Cc 128
#define Nn 2
#define KK 81
#define HW (Hh * Ww)          // 4096
#define CHW (Cc * HW)         // 524288
#define P_TOT (Nn * HW)       // 8192

typedef _Float16 h8 __attribute__((ext_vector_type(8)));
typedef _Float16 h4 __attribute__((ext_vector_type(4)));
typedef float f4v __attribute__((ext_vector_type(4)));

// ---------------- Kernel A: projection via MFMA (measured-best version, unchanged).
__global__ __launch_bounds__(256) void proj_kernel(const float* __restrict__ ft,
                                                   const float* __restrict__ fk,
                                                   const float* __restrict__ Wm,
                                                   _Float16* __restrict__ Qbuf,
                                                   _Float16* __restrict__ Kbuf,
                                                   _Float16* __restrict__ fth) {
    __shared__ __align__(16) _Float16 Wth[128 * 136];  // [o][i] fp16 (== B[k][n] view)
    __shared__ __align__(16) _Float16 xkh[32 * 136];   // [px][c] fp16
    __shared__ __align__(16) _Float16 xqh[32 * 136];
    const int t = threadIdx.x;
    const int p0 = blockIdx.x * 32;       // 4096 % 32 == 0: never crosses n
    const int nn = p0 >> 12;
    const int gbase = nn * CHW + (p0 & 4095);

#pragma unroll 4
    for (int e = t; e < 4096; e += 256) {             // stage W -> fp16
        const int n = e >> 5, ch = e & 31;
        const float4 v = *(const float4*)&Wm[n * 128 + (ch << 2)];
        h4 hv; hv[0] = (_Float16)v.x; hv[1] = (_Float16)v.y;
               hv[2] = (_Float16)v.z; hv[3] = (_Float16)v.w;
        *(h4*)&Wth[n * 136 + (ch << 2)] = hv;
    }
#pragma unroll 4
    for (int e = t; e < 1024; e += 256) {             // stage x -> fp16 px-major
        const int c = e >> 3, pc = e & 7;
        const float4 vk = *(const float4*)&ft[gbase + c * HW + (pc << 2)];
        const float4 vq = *(const float4*)&fk[gbase + c * HW + (pc << 2)];
        const int px = pc << 2;
        xkh[(px    ) * 136 + c] = (_Float16)vk.x;
        xkh[(px + 1) * 136 + c] = (_Float16)vk.y;
        xkh[(px + 2) * 136 + c] = (_Float16)vk.z;
        xkh[(px + 3) * 136 + c] = (_Float16)vk.w;
        xqh[(px    ) * 136 + c] = (_Float16)vq.x;
        xqh[(px + 1) * 136 + c] = (_Float16)vq.y;
        xqh[(px + 2) * 136 + c] = (_Float16)vq.z;
        xqh[(px + 3) * 136 + c] = (_Float16)vq.w;
    }
    __syncthreads();

#pragma unroll
    for (int e = t; e < 512; e += 256) {              // fth: coalesced h8 copies
        const int px = e >> 4, cq = e & 15;
        *(h8*)&fth[(size_t)(p0 + px) * 128 + (cq << 3)] =
            *(const h8*)&xkh[px * 136 + (cq << 3)];
    }

    const int lane = t & 63, wv = t >> 6;
    const int quad = lane >> 4, l15 = lane & 15;
    const _Float16* xs = (wv >> 1) ? xqh : xkh;
    _Float16* dst = (wv >> 1) ? Qbuf : Kbuf;
    const int mt = wv & 1;
    const int abase = (mt * 16 + l15) * 136 + (quad << 3);
    const h8 a0 = *(const h8*)&xs[abase];
    const h8 a1 = *(const h8*)&xs[abase + 32];
    const h8 a2 = *(const h8*)&xs[abase + 64];
    const h8 a3 = *(const h8*)&xs[abase + 96];
#pragma unroll
    for (int nt = 0; nt < 8; ++nt) {
        const int bbase = (nt * 16 + l15) * 136 + (quad << 3);
        const h8 b0 = *(const h8*)&Wth[bbase];
        const h8 b1 = *(const h8*)&Wth[bbase + 32];
        const h8 b2 = *(const h8*)&Wth[bbase + 64];
        const h8 b3 = *(const h8*)&Wth[bbase + 96];
        f4v acc = {0.f, 0.f, 0.f, 0.f};
        acc = __builtin_amdgcn_mfma_f32_16x16x32_f16(a0, b0, acc, 0, 0, 0);
        acc = __builtin_amdgcn_mfma_f32_16x16x32_f16(a1, b1, acc, 0, 0, 0);
        acc = __builtin_amdgcn_mfma_f32_16x16x32_f16(a2, b2, acc, 0, 0, 0);
        acc = __builtin_amdgcn_mfma_f32_16x16x32_f16(a3, b3, acc, 0, 0, 0);
        const int col = nt * 16 + l15;
        const size_t rb = (size_t)(p0 + mt * 16 + (quad << 2)) * 128 + col;
#pragma unroll
        for (int r = 0; r < 4; ++r)
            dst[rb + (size_t)r * 128] = (_Float16)acc[r];
    }
}

// ---------------- Kernel B (fused): MFMA dots + softmax + weighting. 8-px row strip.
// Measured-best structure (6 barriers, stride-136 ftl, scalar w reads) + prefetch.
__global__ __launch_bounds__(256, 4) void sim_weight_kernel(const _Float16* __restrict__ Qbuf,
                                                            const _Float16* __restrict__ Kbuf,
                                                            const _Float16* __restrict__ fth,
                                                            float* __restrict__ out) {
    __shared__ __align__(16) unsigned char smem[40720];
    _Float16* Ksw  = (_Float16*)smem;             // 18432 halves [0, 36864)
    _Float16* Qsw  = (_Float16*)(smem + 36864);   // 1024 halves  [36864, 38912); dead after dots
    _Float16* ftl  = (_Float16*)smem;             // [row][c] stride 136: 19584 halves [0,39168)
    float*    simbF= (float*)smem;                // [k][8] fp32, 2592 B — alive B2a..B2c only
    _Float16* simb = (_Float16*)(smem + 39168);   // 648 halves   [39168, 40464)
    float*    redM = (float*)(smem + 40464);      // 32 floats
    float*    redS = (float*)(smem + 40592);      // 32 floats

    const int t  = threadIdx.x;
    const int b  = blockIdx.x;
    const int x0 = (b & 7) << 3;
    const int y  = (b >> 3) & 63;
    const int nn = b >> 9;
    const int pg0 = (nn << 12) + (y << 6) + x0;

    // ---- stage K: zero-padded 9x16 window, h8 copies, XOR-swizzled slots
#pragma unroll 3
    for (int e = t; e < 144 * 16; e += 256) {
        const int v = e >> 4, ci = e & 15;
        const int gx = x0 + (v & 15) - 4;
        const int gy = y + (v >> 4) - 4;
        h8 val = {0, 0, 0, 0, 0, 0, 0, 0};
        if ((unsigned)gx < 64u && (unsigned)gy < 64u)
            val = *(const h8*)&Kbuf[(size_t)((nn << 12) + (gy << 6) + gx) * 128 + (ci << 3)];
        *(h8*)&Ksw[(v << 7) + ((ci ^ (v & 15)) << 3)] = val;
    }
    if (t < 128) {   // stage Q: 8 vectors x 16 chunks
        const int v = t >> 4, ci = t & 15;
        *(h8*)&Qsw[(v << 7) + ((ci ^ v) << 3)] =
            *(const h8*)&Qbuf[(size_t)(pg0 + v) * 128 + (ci << 3)];
    }
    __syncthreads();   // B1

    // ---- PREFETCH ftl source data into registers: overlaps the whole dot phase
    h8 pf[9];
#pragma unroll
    for (int i = 0; i < 9; ++i) {
        const int e = t + (i << 8);               // 9*256 == 144*16 exactly
        const int v = e >> 4, ci = e & 15;
        const int gx = x0 + (v & 15) - 4;
        const int gy = y + (v >> 4) - 4;
        h8 val = {0, 0, 0, 0, 0, 0, 0, 0};
        if ((unsigned)gx < 64u && (unsigned)gy < 64u)
            val = *(const h8*)&fth[(size_t)((nn << 12) + (gy << 6) + gx) * 128 + (ci << 3)];
        pf[i] = val;
    }

    // ---- dots via MFMA: per r, S_r[xx][p] = sum_c Ksw[r*16+xx][c] * Q[p][c]
    // D: row=xx=quad*4+reg, col=p=lane&15 [R13 HW-verified layout].
    const int lane = t & 63, wv = t >> 6;
    const int quad = lane >> 4, l15 = lane & 15;
    const int qrow = l15 & 7;                 // clamp: cols 8-15 duplicate, never extracted
    h8 qb[4];
#pragma unroll
    for (int kc = 0; kc < 4; ++kc) {
        const int ci = (kc << 2) + quad;
        qb[kc] = *(const h8*)&Qsw[(qrow << 7) + ((ci ^ qrow) << 3)];
    }
    const int r0 = wv, r1 = wv + 4;           // r2 = 8 computed by all, extracted by wave 0
    f4v acc0 = {0.f,0.f,0.f,0.f}, acc1 = acc0, acc2 = acc0;
#pragma unroll
    for (int kc = 0; kc < 4; ++kc) {
        const int ci = (kc << 2) + quad;
        const h8 kA = *(const h8*)&Ksw[(((r0 << 4) + l15) << 7) + ((ci ^ l15) << 3)];
        const h8 kB = *(const h8*)&Ksw[(((r1 << 4) + l15) << 7) + ((ci ^ l15) << 3)];
        const h8 kC = *(const h8*)&Ksw[(((8  << 4) + l15) << 7) + ((ci ^ l15) << 3)];
        acc0 = __builtin_amdgcn_mfma_f32_16x16x32_f16(kA, qb[kc], acc0, 0, 0, 0);
        acc1 = __builtin_amdgcn_mfma_f32_16x16x32_f16(kB, qb[kc], acc1, 0, 0, 0);
        acc2 = __builtin_amdgcn_mfma_f32_16x16x32_f16(kC, qb[kc], acc2, 0, 0, 0);
    }
    __syncthreads();   // B2a: MFMA reads done; Ksw/Qsw dead -> simbF may be written

    // extraction: valid iff p=l15<8 and dx=xx-p in [0,9); k = r*9+dx
#pragma unroll
    for (int reg = 0; reg < 4; ++reg) {
        const int xx = (quad << 2) + reg;
        const int dx = xx - l15;
        const bool ok = (l15 < 8) && (dx >= 0) && (dx < 9);
        if (ok)            simbF[(r0 * 9 + dx) * 8 + l15] = acc0[reg];
        if (ok)            simbF[(r1 * 9 + dx) * 8 + l15] = acc1[reg];
        if (ok && wv == 0) simbF[(8  * 9 + dx) * 8 + l15] = acc2[reg];
    }
    __syncthreads();   // B2b: simbF complete

    const int p = t & 7, kb = t >> 3;
    const bool has2 = (kb + 64 < KK);
    const float s0 = simbF[kb * 8 + p];
    const float s1 = simbF[(kb + 32) * 8 + p];
    const float s2 = has2 ? simbF[(kb + 64) * 8 + p] : 0.f;
    __syncthreads();   // B2c: readback done; ftl may overwrite [0, 39168)

    // ---- restage ft from PREFETCHED registers (no global loads here)
#pragma unroll
    for (int i = 0; i < 9; ++i) {
        const int e = t + (i << 8);
        const int v = e >> 4, ci = e & 15;
        *(h8*)&ftl[v * 136 + (ci << 3)] = pf[i];
    }

    // ---- softmax in registers: reduce over lanes sharing p (bits 3..5 of lane id)
    float m = fmaxf(s0, s1);
    if (has2) m = fmaxf(m, s2);
#pragma unroll
    for (int off = 8; off <= 32; off <<= 1) m = fmaxf(m, __shfl_xor(m, off));
    if ((t & 56) == 0) redM[((t >> 6) << 3) + p] = m;   // one lane per (wave, p)
    __syncthreads();   // B3 (also covers ftl writes)
    float mm = fmaxf(fmaxf(redM[p], redM[8 + p]), fmaxf(redM[16 + p], redM[24 + p]));
    const float e0 = __expf(s0 - mm);
    const float e1 = __expf(s1 - mm);
    const float e2 = has2 ? __expf(s2 - mm) : 0.f;
    simb[kb * 8 + p] = (_Float16)e0;
    simb[(kb + 32) * 8 + p] = (_Float16)e1;
    if (has2) simb[(kb + 64) * 8 + p] = (_Float16)e2;
    float s = e0 + e1 + e2;
#pragma unroll
    for (int off = 8; off <= 32; off <<= 1) s += __shfl_xor(s, off);
    if ((t & 56) == 0) redS[((t >> 6) << 3) + p] = s;
    __syncthreads();   // B4
    const float inv = 1.f / (redS[p] + redS[8 + p] + redS[16 + p] + redS[24 + p]);

    // ---- weighting: thread = (p, cq); 4 channels per thread, fp16 ftl, fp32 accum
    const int cq = t >> 3;
    float4 acc = make_float4(0, 0, 0, 0);
    for (int r = 0; r < 9; ++r) {
        const int rb = ((r << 4) + p) * 136 + (cq << 2);
        const int k9 = r * 9;
#pragma unroll
        for (int dx = 0; dx < 9; ++dx) {
            const float w = (float)simb[(k9 + dx) * 8 + p];  // 8-lane broadcast
            const h4 f = *(const h4*)&ftl[rb + dx * 136];
            acc.x += (float)f[0] * w;
            acc.y += (float)f[1] * w;
            acc.z += (float)f[2] * w;
            acc.w += (float)f[3] * w;
        }
    }
    const size_t ob = (size_t)((nn * Cc + (cq << 2)) << 12) + (y << 6) + x0 + p;
    out[ob]          = acc.x * inv;
    out[ob + HW]     = acc.y * inv;
    out[ob + 2*HW]   = acc.z * inv;
    out[ob + 3*HW]   = acc.w * inv;
}

extern "C" void kernel_launch(void* const* d_in, const int* in_sizes, int n_in,
                              void* d_out, int out_size, void* d_ws, size_t ws_size,
                              hipStream_t stream) {
    const float* ft = (const float*)d_in[0];
    const float* fk = (const float*)d_in[1];
    const float* Wm = (const float*)d_in[2];
    float* out = (float*)d_out;

    _Float16* wsh  = (_Float16*)d_ws;    // 6 MB: Qh(2MB) + Kh(2MB) + fth(2MB)
    _Float16* Qbuf = wsh;                // [p][c]  8192*128 halves
    _Float16* Kbuf = wsh + 1048576;      // [p][c]  8192*128 halves
    _Float16* fth  = wsh + 2097152;      // fp16 ft, PIXEL-MAJOR [p][c]

    proj_kernel<<<256, 256, 0, stream>>>(ft, fk, Wm, Qbuf, Kbuf, fth);
    sim_weight_kernel<<<1024, 256, 0, stream>>>(Qbuf, Kbuf, fth, out);
}